// Round 1
// baseline (1074.255 us; speedup 1.0000x reference)
//
#include <hip/hip_runtime.h>

#define NA 50000
#define NE 1600000
#define NK 2048
#define NL 6

typedef __attribute__((ext_vector_type(8))) short short8;
typedef __attribute__((ext_vector_type(4))) float f32x4;
typedef unsigned short u16;
typedef unsigned int u32;

__device__ __forceinline__ float bf2f(u16 b){ union{u32 i;float f;}v; v.i=((u32)b)<<16; return v.f; }
__device__ __forceinline__ u16 f2bf(float f){ union{float f;u32 i;}v; v.f=f; u32 x=v.i; return (u16)((x + 0x7fffu + ((x>>16)&1u))>>16); }
__device__ __forceinline__ float sspf(float x){ return __logf(1.f+__expf(x)) - 0.69314718056f; }

struct __align__(16) EPrm { int col; int j; float u0; float u1; };

// ---------------- prep: transpose node weights to bf16 [f_out][k] ----------------
__global__ __launch_bounds__(256) void k_prep_w(const float* __restrict__ l1,
    const float* __restrict__ l2, const float* __restrict__ il,
    u16* __restrict__ l1t, u16* __restrict__ l2t, u16* __restrict__ ilt)
{
  int t = blockIdx.x*256 + threadIdx.x;
  if (t >= 3*NL*16384) return;
  int sec = t / (NL*16384);
  int r = t % (NL*16384);
  int l = r / 16384, q = r & 16383;
  int fo = q >> 7, k = q & 127;
  const float* src = sec==0 ? l1 : (sec==1 ? l2 : il);
  u16* dst = sec==0 ? l1t : (sec==1 ? l2t : ilt);
  dst[r] = f2bf(src[l*16384 + k*128 + fo]);
}

// ---------------- prep: per-edge distance -> (col, knot j, lerp*cutoff weights) ----------------
__global__ __launch_bounds__(256) void k_prep_e(const float* __restrict__ pos,
    const int* __restrict__ ei, EPrm* __restrict__ ep)
{
  int e = blockIdx.x*256 + threadIdx.x;
  if (e >= NE) return;
  int r = ei[e], c = ei[NE+e];
  float dx = pos[r*3+0]-pos[c*3+0];
  float dy = pos[r*3+1]-pos[c*3+1];
  float dz = pos[r*3+2]-pos[c*3+2];
  float d = sqrtf(dx*dx+dy*dy+dz*dz);
  float C = 0.5f*(cosf(d*0.31415926535f)+1.0f);
  float s = d * ((float)(NK-1) / 8.6603f);
  int j = (int)s;
  if (j > NK-2) j = NK-2;
  float w = s - (float)j;
  EPrm p; p.col=c; p.j=j; p.u0=C*(1.f-w); p.u1=C*w;
  ep[e]=p;
}

// ---------------- embedding gather ----------------
__global__ __launch_bounds__(256) void k_embed(const int* __restrict__ z,
    const float* __restrict__ emb, float* __restrict__ h)
{
  int t = blockIdx.x*256+threadIdx.x;
  if (t >= NA*128) return;
  h[t] = emb[z[t>>7]*128 + (t&127)];
}

// ---------------- filter table: T[l][j][f] = (ssp(rbf(d_j)@W1+b1)@W2+b2)[f], exact fp32 ----------------
__global__ __launch_bounds__(128) void k_table(const float* __restrict__ w1,
    const float* __restrict__ b1, const float* __restrict__ w2,
    const float* __restrict__ b2, float* __restrict__ T)
{
  int l = blockIdx.x / NK, j = blockIdx.x % NK;
  __shared__ float rbf_s[50];
  __shared__ float h1_s[128];
  int t = threadIdx.x;
  float d = (float)j * (8.6603f/(float)(NK-1));
  if (t < 50){
    const float step = 10.0f/49.0f;
    const float coeff = -0.5f/(step*step);
    float dd = d - (float)t*step;
    rbf_s[t] = expf(coeff*dd*dd);
  }
  __syncthreads();
  const float* W1 = w1 + l*50*128;
  float acc = b1[l*128+t];
  for (int g=0; g<50; g++) acc += rbf_s[g]*W1[g*128+t];
  h1_s[t] = logf(1.0f+expf(acc)) - 0.69314718055994531f;
  __syncthreads();
  const float* W2 = w2 + l*128*128;
  float a2 = b2[l*128+t];
  for (int k=0;k<128;k++) a2 += h1_s[k]*W2[k*128+t];
  T[((size_t)l*NK + j)*128 + t] = a2;
}

// ---------------- shared GEMM pieces (128x128 tile, bf16 MFMA, XOR-swizzled LDS) ----------------
__device__ __forceinline__ void stage_a_f32(const float* __restrict__ g, u16* l, int r0, int t){
  #pragma unroll
  for (int p=0;p<8;p++){
    int idx = p*256+t;
    int row = idx>>4, c = idx&15;
    int gr = r0+row;
    float4 f0 = make_float4(0.f,0.f,0.f,0.f), f1 = make_float4(0.f,0.f,0.f,0.f);
    if (gr < NA){
      const float* gp = g + (size_t)gr*128 + c*8;
      f0 = *(const float4*)gp;
      f1 = *(const float4*)(gp+4);
    }
    short8 v;
    u16* pv=(u16*)&v;
    pv[0]=f2bf(f0.x); pv[1]=f2bf(f0.y); pv[2]=f2bf(f0.z); pv[3]=f2bf(f0.w);
    pv[4]=f2bf(f1.x); pv[5]=f2bf(f1.y); pv[6]=f2bf(f1.z); pv[7]=f2bf(f1.w);
    *(short8*)(l + row*128 + ((c^(row&7))<<3)) = v;
  }
}

__device__ __forceinline__ void stage_b_bf16(const u16* __restrict__ g, u16* l, int t){
  const short8* src = (const short8*)g;
  #pragma unroll
  for (int p=0;p<8;p++){
    int idx=p*256+t;
    int row=idx>>4, c=idx&15;
    short8 v = src[idx];
    *(short8*)(l + row*128 + ((c^(row&7))<<3)) = v;
  }
}

__device__ __forceinline__ void zacc(f32x4 (&acc)[4][4]){
  #pragma unroll
  for (int m=0;m<4;m++)
    #pragma unroll
    for (int n=0;n<4;n++){
      acc[m][n][0]=0.f; acc[m][n][1]=0.f; acc[m][n][2]=0.f; acc[m][n][3]=0.f;
    }
}

__device__ __forceinline__ void gemm128(const u16* A, const u16* B, f32x4 (&acc)[4][4], int lane, int wm, int wn){
  const int lr = lane&15, lk = lane>>4;
  #pragma unroll
  for (int kc=0;kc<4;kc++){
    short8 av[4], bv[4];
    #pragma unroll
    for (int m=0;m<4;m++){
      int row = wm*64+m*16+lr;
      av[m] = *(const short8*)(A + row*128 + ((((kc<<2)|lk) ^ (row&7))<<3));
    }
    #pragma unroll
    for (int n=0;n<4;n++){
      int row = wn*64+n*16+lr;
      bv[n] = *(const short8*)(B + row*128 + ((((kc<<2)|lk) ^ (row&7))<<3));
    }
    #pragma unroll
    for (int m=0;m<4;m++)
      #pragma unroll
      for (int n=0;n<4;n++)
        acc[m][n] = __builtin_amdgcn_mfma_f32_16x16x32_bf16(av[m], bv[n], acc[m][n], 0, 0, 0);
  }
}

// ---------------- x = bf16(h @ lin1_w[l]) ----------------
__global__ __launch_bounds__(256) void k_lin1(const float* __restrict__ h,
    const u16* __restrict__ wt, u16* __restrict__ x)
{
  extern __shared__ char smem[];
  u16* a_s = (u16*)smem;
  u16* b_s = a_s + 16384;
  int t = threadIdx.x, lane = t&63, wid = t>>6;
  int r0 = blockIdx.x*128;
  stage_a_f32(h, a_s, r0, t);
  stage_b_bf16(wt, b_s, t);
  __syncthreads();
  f32x4 acc[4][4]; zacc(acc);
  int wm=wid>>1, wn=wid&1;
  gemm128(a_s,b_s,acc,lane,wm,wn);
  int lr=lane&15, lk=lane>>4;
  #pragma unroll
  for (int n=0;n<4;n++){
    int f = wn*64+n*16+lr;
    #pragma unroll
    for (int m=0;m<4;m++){
      int rb = wm*64+m*16+(lk<<2);
      #pragma unroll
      for (int i=0;i<4;i++){
        int gr = r0+rb+i;
        if (gr < NA) x[(size_t)gr*128+f] = f2bf(acc[m][n][i]);
      }
    }
  }
}

// ---------------- per-edge: agg[a][f] = sum_e lerp(T,d_e)[f]*C_e*x[col_e][f] ----------------
__global__ __launch_bounds__(256) void k_edge(const EPrm* __restrict__ ep,
    const u16* __restrict__ x, const float* __restrict__ T, float* __restrict__ agg)
{
  __shared__ EPrm eps[256];
  int t=threadIdx.x, lane=t&63, wid=t>>6;
  ((int4*)eps)[t] = ((const int4*)(ep + (size_t)blockIdx.x*256))[t];
  __syncthreads();
  #pragma unroll 1
  for (int p=0;p<2;p++){
    float acc0=0.f, acc1=0.f;
    int base = (wid*2+p)*32;
    #pragma unroll 4
    for (int e=0;e<32;e++){
      EPrm pr = eps[base+e];
      const float* tr = T + ((size_t)pr.j<<7);
      const u16* xr = x + ((size_t)pr.col<<7);
      float2 t0 = *(const float2*)(tr + (lane<<1));
      float2 t1 = *(const float2*)(tr + 128 + (lane<<1));
      u32 xv = *(const u32*)(xr + (lane<<1));
      float w0 = pr.u0*t0.x + pr.u1*t1.x;
      float w1 = pr.u0*t0.y + pr.u1*t1.y;
      union{u32 i;float f;} ua, ub;
      ua.i = xv<<16; ub.i = xv & 0xffff0000u;
      acc0 += w0*ua.f;
      acc1 += w1*ub.f;
    }
    int atom = blockIdx.x*8 + wid*2 + p;
    float2 o; o.x=acc0; o.y=acc1;
    *(float2*)(agg + ((size_t)atom<<7) + (lane<<1)) = o;
  }
}

// ---------------- h += ssp(agg@lin2+b)@int_lin + b ----------------
__global__ __launch_bounds__(256) void k_node(const float* __restrict__ agg,
    const u16* __restrict__ l2t, const float* __restrict__ l2b,
    const u16* __restrict__ ilt, const float* __restrict__ ilb,
    float* __restrict__ h)
{
  extern __shared__ char smem[];
  u16* a_s=(u16*)smem; u16* b_s=a_s+16384;
  int t=threadIdx.x, lane=t&63, wid=t>>6;
  int r0=blockIdx.x*128;
  stage_a_f32(agg, a_s, r0, t);
  stage_b_bf16(l2t, b_s, t);
  __syncthreads();
  f32x4 acc[4][4]; zacc(acc);
  int wm=wid>>1, wn=wid&1, lr=lane&15, lk=lane>>4;
  gemm128(a_s,b_s,acc,lane,wm,wn);
  __syncthreads();
  #pragma unroll
  for (int n=0;n<4;n++){
    int f=wn*64+n*16+lr;
    float bb=l2b[f];
    #pragma unroll
    for (int m=0;m<4;m++){
      int rb=wm*64+m*16+(lk<<2);
      #pragma unroll
      for (int i=0;i<4;i++){
        int r=rb+i;
        float v=sspf(acc[m][n][i]+bb);
        a_s[r*128 + (((f>>3)^(r&7))<<3) + (f&7)] = f2bf(v);
      }
    }
  }
  stage_b_bf16(ilt, b_s, t);
  __syncthreads();
  f32x4 acc2[4][4]; zacc(acc2);
  gemm128(a_s,b_s,acc2,lane,wm,wn);
  #pragma unroll
  for (int n=0;n<4;n++){
    int f=wn*64+n*16+lr;
    float bb=ilb[f];
    #pragma unroll
    for (int m=0;m<4;m++){
      int rb=wm*64+m*16+(lk<<2);
      #pragma unroll
      for (int i=0;i<4;i++){
        int gr=r0+rb+i;
        if (gr<NA){
          size_t o=(size_t)gr*128+f;
          h[o] += acc2[m][n][i]+bb;
        }
      }
    }
  }
}

// ---------------- prediction head: 128 -> 64 -> 32 -> 1 with PReLU ----------------
__global__ __launch_bounds__(256) void k_head(const float* __restrict__ h,
  const float* __restrict__ hw1, const float* __restrict__ hb1, const float* __restrict__ a1p,
  const float* __restrict__ hw2, const float* __restrict__ hb2, const float* __restrict__ a2p,
  const float* __restrict__ hw3, const float* __restrict__ hb3, float* __restrict__ out)
{
  __shared__ float w1_s[128*64];
  __shared__ float w2_s[64*32];
  __shared__ float w3_s[32];
  __shared__ float b1_s[64], b2_s[32];
  __shared__ float row_s[4][128];
  __shared__ float y1_s[4][64];
  __shared__ float y2_s[4][32];
  int t=threadIdx.x, lane=t&63, wid=t>>6;
  for (int i=t;i<8192;i+=256) w1_s[i]=hw1[i];
  for (int i=t;i<2048;i+=256) w2_s[i]=hw2[i];
  if (t<32) w3_s[t]=hw3[t];
  if (t<64) b1_s[t]=hb1[t];
  if (t<32) b2_s[t]=hb2[t];
  float A1=a1p[0], A2=a2p[0], B3=hb3[0];
  __syncthreads();
  for (int it=0; it<8; it++){
    int a = blockIdx.x*32 + wid*8 + it;
    float v0=0.f,v1=0.f;
    if (a<NA){ v0=h[(size_t)a*128+lane]; v1=h[(size_t)a*128+64+lane]; }
    row_s[wid][lane]=v0; row_s[wid][64+lane]=v1;
    __syncthreads();
    float acc = b1_s[lane];
    for (int k=0;k<128;k++) acc += row_s[wid][k]*w1_s[k*64+lane];
    acc = acc>=0.f ? acc : A1*acc;
    y1_s[wid][lane] = acc;
    __syncthreads();
    float acc2 = b2_s[lane&31];
    for (int k=0;k<64;k++) acc2 += y1_s[wid][k]*w2_s[k*32+(lane&31)];
    acc2 = acc2>=0.f ? acc2 : A2*acc2;
    if (lane<32) y2_s[wid][lane]=acc2;
    __syncthreads();
    if (lane<32){
      float psum = y2_s[wid][lane]*w3_s[lane];
      psum += __shfl_xor(psum,1); psum += __shfl_xor(psum,2); psum += __shfl_xor(psum,4);
      psum += __shfl_xor(psum,8); psum += __shfl_xor(psum,16);
      if (lane==0 && a<NA) out[a] = psum + B3;
    }
    __syncthreads();
  }
}

extern "C" void kernel_launch(void* const* d_in, const int* in_sizes, int n_in,
                              void* d_out, int out_size, void* d_ws, size_t ws_size,
                              hipStream_t stream) {
  (void)in_sizes; (void)n_in; (void)out_size; (void)ws_size;
  const int*   z    = (const int*)  d_in[0];
  const float* pos  = (const float*)d_in[1];
  const int*   ei   = (const int*)  d_in[2];
  const float* emb  = (const float*)d_in[3];
  const float* mw1  = (const float*)d_in[4];
  const float* mb1  = (const float*)d_in[5];
  const float* mw2  = (const float*)d_in[6];
  const float* mb2  = (const float*)d_in[7];
  const float* l1w  = (const float*)d_in[8];
  const float* l2w  = (const float*)d_in[9];
  const float* l2b  = (const float*)d_in[10];
  const float* ilw  = (const float*)d_in[11];
  const float* ilb  = (const float*)d_in[12];
  const float* hw1  = (const float*)d_in[13];
  const float* hb1  = (const float*)d_in[14];
  const float* a1   = (const float*)d_in[15];
  const float* hw2  = (const float*)d_in[16];
  const float* hb2  = (const float*)d_in[17];
  const float* a2   = (const float*)d_in[18];
  const float* hw3  = (const float*)d_in[19];
  const float* hb3  = (const float*)d_in[20];
  float* out = (float*)d_out;

  char* w = (char*)d_ws;
  EPrm* ep  = (EPrm*)w;  w += (size_t)NE*16;
  float* h  = (float*)w; w += (size_t)NA*128*4;
  float* agg= (float*)w; w += (size_t)NA*128*4;
  u16*  x   = (u16*)w;   w += (size_t)NA*128*2;
  float* T  = (float*)w; w += (size_t)NL*NK*128*4;
  u16* l1t  = (u16*)w;   w += (size_t)NL*16384*2;
  u16* l2t  = (u16*)w;   w += (size_t)NL*16384*2;
  u16* ilt  = (u16*)w;   w += (size_t)NL*16384*2;

  k_prep_w<<<(3*NL*16384+255)/256, 256, 0, stream>>>(l1w, l2w, ilw, l1t, l2t, ilt);
  k_table<<<NL*NK, 128, 0, stream>>>(mw1, mb1, mw2, mb2, T);
  k_prep_e<<<NE/256, 256, 0, stream>>>(pos, ei, ep);
  k_embed<<<NA*128/256, 256, 0, stream>>>(z, emb, h);
  for (int l=0;l<NL;l++){
    k_lin1<<<(NA+127)/128, 256, 65536, stream>>>(h, l1t + l*16384, x);
    k_edge<<<NA/8, 256, 0, stream>>>(ep, x, T + (size_t)l*NK*128, agg);
    k_node<<<(NA+127)/128, 256, 65536, stream>>>(agg, l2t+l*16384, l2b+l*128, ilt+l*16384, ilb+l*128, h);
  }
  k_head<<<(NA+31)/32, 256, 0, stream>>>(h, hw1, hb1, a1, hw2, hb2, a2, hw3, hb3, out);
}

// Round 2
// 733.872 us; speedup vs baseline: 1.4638x; 1.4638x over previous
//
#include <hip/hip_runtime.h>

#define NA 50000
#define NAP 50048
#define NE 1600000
#define NK 2048
#define NL 6

typedef __attribute__((ext_vector_type(8))) short short8;
typedef __attribute__((ext_vector_type(4))) float f32x4;
typedef unsigned short u16;
typedef unsigned int u32;

__device__ __forceinline__ float bf2f(u16 b){ union{u32 i;float f;}v; v.i=((u32)b)<<16; return v.f; }
__device__ __forceinline__ u16 f2bf(float f){ union{float f;u32 i;}v; v.f=f; u32 x=v.i; return (u16)((x + 0x7fffu + ((x>>16)&1u))>>16); }
__device__ __forceinline__ float sspf(float x){ return __logf(1.f+__expf(x)) - 0.69314718056f; }

// ---------------- prep: transpose node weights to bf16 [f_out][k] ----------------
__global__ __launch_bounds__(256) void k_prep_w(const float* __restrict__ l1,
    const float* __restrict__ l2, const float* __restrict__ il,
    u16* __restrict__ l1t, u16* __restrict__ l2t, u16* __restrict__ ilt)
{
  int t = blockIdx.x*256 + threadIdx.x;
  if (t >= 3*NL*16384) return;
  int sec = t / (NL*16384);
  int r = t % (NL*16384);
  int l = r / 16384, q = r & 16383;
  int fo = q >> 7, k = q & 127;
  const float* src = sec==0 ? l1 : (sec==1 ? l2 : il);
  u16* dst = sec==0 ? l1t : (sec==1 ? l2t : ilt);
  dst[r] = f2bf(src[l*16384 + k*128 + fo]);
}

// ---------------- prep: per-edge distance -> packed (col|j<<17, fp16 u0,u1) ----------------
__global__ __launch_bounds__(256) void k_prep_e(const float* __restrict__ pos,
    const int* __restrict__ ei, uint2* __restrict__ ep2)
{
  int e = blockIdx.x*256 + threadIdx.x;
  if (e >= NE) return;
  int r = ei[e], c = ei[NE+e];
  float dx = pos[r*3+0]-pos[c*3+0];
  float dy = pos[r*3+1]-pos[c*3+1];
  float dz = pos[r*3+2]-pos[c*3+2];
  float d = sqrtf(dx*dx+dy*dy+dz*dz);
  float C = 0.5f*(cosf(d*0.31415926535f)+1.0f);
  float s = d * ((float)(NK-1) / 8.6603f);
  int j = (int)s;
  if (j > NK-2) j = NK-2;
  float w = s - (float)j;
  float u0 = C*(1.f-w), u1 = C*w;
  union { _Float16 h[2]; u32 u; } p;
  p.h[0] = (_Float16)u0; p.h[1] = (_Float16)u1;
  uint2 o; o.x = (u32)c | ((u32)j<<17); o.y = p.u;
  ep2[e] = o;
}

// ---------------- embedding gather ----------------
__global__ __launch_bounds__(256) void k_embed(const int* __restrict__ z,
    const float* __restrict__ emb, float* __restrict__ h)
{
  int t = blockIdx.x*256+threadIdx.x;
  if (t >= NA*128) return;
  h[t] = emb[z[t>>7]*128 + (t&127)];
}

// ---------------- filter table: T[l][j][f] = (ssp(rbf(d_j)@W1+b1)@W2+b2)[f], exact fp32 ----------------
__global__ __launch_bounds__(128) void k_table(const float* __restrict__ w1,
    const float* __restrict__ b1, const float* __restrict__ w2,
    const float* __restrict__ b2, float* __restrict__ T)
{
  int l = blockIdx.x / NK, j = blockIdx.x % NK;
  __shared__ float rbf_s[50];
  __shared__ float h1_s[128];
  int t = threadIdx.x;
  float d = (float)j * (8.6603f/(float)(NK-1));
  if (t < 50){
    const float step = 10.0f/49.0f;
    const float coeff = -0.5f/(step*step);
    float dd = d - (float)t*step;
    rbf_s[t] = expf(coeff*dd*dd);
  }
  __syncthreads();
  const float* W1 = w1 + l*50*128;
  float acc = b1[l*128+t];
  for (int g=0; g<50; g++) acc += rbf_s[g]*W1[g*128+t];
  h1_s[t] = logf(1.0f+expf(acc)) - 0.69314718055994531f;
  __syncthreads();
  const float* W2 = w2 + l*128*128;
  float a2 = b2[l*128+t];
  for (int k=0;k<128;k++) a2 += h1_s[k]*W2[k*128+t];
  T[((size_t)l*NK + j)*128 + t] = a2;
}

// ---------------- pack table to bf16 knot-pairs: T2[j][f] = (T[j][f], T[j+1][f]) ----------------
__global__ __launch_bounds__(256) void k_pack(const float* __restrict__ T, u32* __restrict__ T2)
{
  int t = blockIdx.x*256 + threadIdx.x;
  if (t >= NL*NK*128) return;
  int jj = (t>>7) & (NK-1);
  float a = T[t];
  float b = (jj < NK-1) ? T[t+128] : a;
  T2[t] = (u32)f2bf(a) | ((u32)f2bf(b)<<16);
}

// ---------------- shared GEMM pieces (128x128 tile, bf16 MFMA, XOR-swizzled LDS) ----------------
__device__ __forceinline__ void stage_a_f32(const float* __restrict__ g, u16* l, int r0, int t){
  #pragma unroll
  for (int p=0;p<8;p++){
    int idx = p*256+t;
    int row = idx>>4, c = idx&15;
    int gr = r0+row;
    float4 f0 = make_float4(0.f,0.f,0.f,0.f), f1 = make_float4(0.f,0.f,0.f,0.f);
    if (gr < NA){
      const float* gp = g + (size_t)gr*128 + c*8;
      f0 = *(const float4*)gp;
      f1 = *(const float4*)(gp+4);
    }
    short8 v;
    u16* pv=(u16*)&v;
    pv[0]=f2bf(f0.x); pv[1]=f2bf(f0.y); pv[2]=f2bf(f0.z); pv[3]=f2bf(f0.w);
    pv[4]=f2bf(f1.x); pv[5]=f2bf(f1.y); pv[6]=f2bf(f1.z); pv[7]=f2bf(f1.w);
    *(short8*)(l + row*128 + ((c^(row&7))<<3)) = v;
  }
}

// A-stage from bf16 source with per-block row offset (source padded to NAP rows)
__device__ __forceinline__ void stage_a_bf16(const u16* __restrict__ g, u16* l, int r0, int t){
  #pragma unroll
  for (int p=0;p<8;p++){
    int idx = p*256+t;
    int row = idx>>4, c = idx&15;
    short8 v = *(const short8*)(g + (size_t)(r0+row)*128 + c*8);
    *(short8*)(l + row*128 + ((c^(row&7))<<3)) = v;
  }
}

__device__ __forceinline__ void stage_b_bf16(const u16* __restrict__ g, u16* l, int t){
  const short8* src = (const short8*)g;
  #pragma unroll
  for (int p=0;p<8;p++){
    int idx=p*256+t;
    int row=idx>>4, c=idx&15;
    short8 v = src[idx];
    *(short8*)(l + row*128 + ((c^(row&7))<<3)) = v;
  }
}

__device__ __forceinline__ void zacc(f32x4 (&acc)[4][4]){
  #pragma unroll
  for (int m=0;m<4;m++)
    #pragma unroll
    for (int n=0;n<4;n++){
      acc[m][n][0]=0.f; acc[m][n][1]=0.f; acc[m][n][2]=0.f; acc[m][n][3]=0.f;
    }
}

__device__ __forceinline__ void gemm128(const u16* A, const u16* B, f32x4 (&acc)[4][4], int lane, int wm, int wn){
  const int lr = lane&15, lk = lane>>4;
  #pragma unroll
  for (int kc=0;kc<4;kc++){
    short8 av[4], bv[4];
    #pragma unroll
    for (int m=0;m<4;m++){
      int row = wm*64+m*16+lr;
      av[m] = *(const short8*)(A + row*128 + ((((kc<<2)|lk) ^ (row&7))<<3));
    }
    #pragma unroll
    for (int n=0;n<4;n++){
      int row = wn*64+n*16+lr;
      bv[n] = *(const short8*)(B + row*128 + ((((kc<<2)|lk) ^ (row&7))<<3));
    }
    #pragma unroll
    for (int m=0;m<4;m++)
      #pragma unroll
      for (int n=0;n<4;n++)
        acc[m][n] = __builtin_amdgcn_mfma_f32_16x16x32_bf16(av[m], bv[n], acc[m][n], 0, 0, 0);
  }
}

// ---------------- x = bf16(h @ lin1_w[l]) ----------------
__global__ __launch_bounds__(256) void k_lin1(const float* __restrict__ h,
    const u16* __restrict__ wt, u16* __restrict__ x)
{
  extern __shared__ char smem[];
  u16* a_s = (u16*)smem;
  u16* b_s = a_s + 16384;
  int t = threadIdx.x, lane = t&63, wid = t>>6;
  int r0 = blockIdx.x*128;
  stage_a_f32(h, a_s, r0, t);
  stage_b_bf16(wt, b_s, t);
  __syncthreads();
  f32x4 acc[4][4]; zacc(acc);
  int wm=wid>>1, wn=wid&1;
  gemm128(a_s,b_s,acc,lane,wm,wn);
  int lr=lane&15, lk=lane>>4;
  #pragma unroll
  for (int n=0;n<4;n++){
    int f = wn*64+n*16+lr;
    #pragma unroll
    for (int m=0;m<4;m++){
      int rb = wm*64+m*16+(lk<<2);
      #pragma unroll
      for (int i=0;i<4;i++){
        int gr = r0+rb+i;
        if (gr < NA) x[(size_t)gr*128+f] = f2bf(acc[m][n][i]);
      }
    }
  }
}

// ---------------- per-edge: aggb[a][f] = bf16( sum_e lerp(T2,d_e)[f]*x[col_e][f] ) ----------------
// 1 wave per atom; 16-lane group per edge (4 edges concurrent); lane covers 4 f per half.
__global__ __launch_bounds__(256) void k_edge(const uint2* __restrict__ ep2,
    const u16* __restrict__ x, const u32* __restrict__ T2, u16* __restrict__ aggb)
{
  __shared__ uint2 eps_s[128];
  int t = threadIdx.x;
  if (t < 128) eps_s[t] = ep2[(size_t)blockIdx.x*128 + t];
  __syncthreads();
  int lane = t&63, wid = t>>6;
  int g = lane>>4, q = lane&15;
  float acc[8];
  #pragma unroll
  for (int i=0;i<8;i++) acc[i]=0.f;
  #pragma unroll
  for (int it=0; it<8; it++){
    uint2 pr = eps_s[wid*32 + it*4 + g];
    u32 col = pr.x & 0x1FFFFu;
    u32 j   = pr.x >> 17;
    union { _Float16 h[2]; u32 u; } uu; uu.u = pr.y;
    float u0 = (float)uu.h[0], u1 = (float)uu.h[1];
    const int4*  tr = (const int4*)(T2 + ((size_t)j<<7));
    const uint2* xr = (const uint2*)(x + ((size_t)col<<7));
    #pragma unroll
    for (int s2=0; s2<2; s2++){
      int4  tv = tr[s2*16+q];
      uint2 xv = xr[s2*16+q];
      u32 tw[4] = {(u32)tv.x,(u32)tv.y,(u32)tv.z,(u32)tv.w};
      u32 xw[2] = {xv.x, xv.y};
      #pragma unroll
      for (int i=0;i<4;i++){
        union{u32 i;float f;} lo, hi, xf;
        lo.i = tw[i]<<16;
        hi.i = tw[i] & 0xffff0000u;
        u32 xq = xw[i>>1];
        xf.i = (i&1) ? (xq & 0xffff0000u) : (xq<<16);
        acc[s2*4+i] += (u0*lo.f + u1*hi.f) * xf.f;
      }
    }
  }
  #pragma unroll
  for (int i=0;i<8;i++){
    acc[i] += __shfl_xor(acc[i],16);
    acc[i] += __shfl_xor(acc[i],32);
  }
  if (lane < 16){
    int a = blockIdx.x*4 + wid;
    #pragma unroll
    for (int s2=0; s2<2; s2++){
      u32 p01 = (u32)f2bf(acc[s2*4+0]) | ((u32)f2bf(acc[s2*4+1])<<16);
      u32 p23 = (u32)f2bf(acc[s2*4+2]) | ((u32)f2bf(acc[s2*4+3])<<16);
      ((uint2*)(aggb + ((size_t)a<<7)))[s2*16+q] = make_uint2(p01,p23);
    }
  }
}

// ---------------- h += ssp(agg@lin2+b)@int_lin + b ----------------
__global__ __launch_bounds__(256) void k_node(const u16* __restrict__ aggb,
    const u16* __restrict__ l2t, const float* __restrict__ l2b,
    const u16* __restrict__ ilt, const float* __restrict__ ilb,
    float* __restrict__ h)
{
  extern __shared__ char smem[];
  u16* a_s=(u16*)smem; u16* b_s=a_s+16384;
  int t=threadIdx.x, lane=t&63, wid=t>>6;
  int r0=blockIdx.x*128;
  stage_a_bf16(aggb, a_s, r0, t);
  stage_b_bf16(l2t, b_s, t);
  __syncthreads();
  f32x4 acc[4][4]; zacc(acc);
  int wm=wid>>1, wn=wid&1, lr=lane&15, lk=lane>>4;
  gemm128(a_s,b_s,acc,lane,wm,wn);
  __syncthreads();
  #pragma unroll
  for (int n=0;n<4;n++){
    int f=wn*64+n*16+lr;
    float bb=l2b[f];
    #pragma unroll
    for (int m=0;m<4;m++){
      int rb=wm*64+m*16+(lk<<2);
      #pragma unroll
      for (int i=0;i<4;i++){
        int r=rb+i;
        float v=sspf(acc[m][n][i]+bb);
        a_s[r*128 + (((f>>3)^(r&7))<<3) + (f&7)] = f2bf(v);
      }
    }
  }
  stage_b_bf16(ilt, b_s, t);
  __syncthreads();
  f32x4 acc2[4][4]; zacc(acc2);
  gemm128(a_s,b_s,acc2,lane,wm,wn);
  #pragma unroll
  for (int n=0;n<4;n++){
    int f=wn*64+n*16+lr;
    float bb=ilb[f];
    #pragma unroll
    for (int m=0;m<4;m++){
      int rb=wm*64+m*16+(lk<<2);
      #pragma unroll
      for (int i=0;i<4;i++){
        int gr=r0+rb+i;
        if (gr<NA){
          size_t o=(size_t)gr*128+f;
          h[o] += acc2[m][n][i]+bb;
        }
      }
    }
  }
}

// ---------------- prediction head: 128 -> 64 -> 32 -> 1 with PReLU ----------------
__global__ __launch_bounds__(256) void k_head(const float* __restrict__ h,
  const float* __restrict__ hw1, const float* __restrict__ hb1, const float* __restrict__ a1p,
  const float* __restrict__ hw2, const float* __restrict__ hb2, const float* __restrict__ a2p,
  const float* __restrict__ hw3, const float* __restrict__ hb3, float* __restrict__ out)
{
  __shared__ float w1_s[128*64];
  __shared__ float w2_s[64*32];
  __shared__ float w3_s[32];
  __shared__ float b1_s[64], b2_s[32];
  __shared__ float row_s[4][128];
  __shared__ float y1_s[4][64];
  __shared__ float y2_s[4][32];
  int t=threadIdx.x, lane=t&63, wid=t>>6;
  for (int i=t;i<8192;i+=256) w1_s[i]=hw1[i];
  for (int i=t;i<2048;i+=256) w2_s[i]=hw2[i];
  if (t<32) w3_s[t]=hw3[t];
  if (t<64) b1_s[t]=hb1[t];
  if (t<32) b2_s[t]=hb2[t];
  float A1=a1p[0], A2=a2p[0], B3=hb3[0];
  __syncthreads();
  for (int it=0; it<8; it++){
    int a = blockIdx.x*32 + wid*8 + it;
    float v0=0.f,v1=0.f;
    if (a<NA){ v0=h[(size_t)a*128+lane]; v1=h[(size_t)a*128+64+lane]; }
    row_s[wid][lane]=v0; row_s[wid][64+lane]=v1;
    __syncthreads();
    float acc = b1_s[lane];
    for (int k=0;k<128;k++) acc += row_s[wid][k]*w1_s[k*64+lane];
    acc = acc>=0.f ? acc : A1*acc;
    y1_s[wid][lane] = acc;
    __syncthreads();
    float acc2 = b2_s[lane&31];
    for (int k=0;k<64;k++) acc2 += y1_s[wid][k]*w2_s[k*32+(lane&31)];
    acc2 = acc2>=0.f ? acc2 : A2*acc2;
    if (lane<32) y2_s[wid][lane]=acc2;
    __syncthreads();
    if (lane<32){
      float psum = y2_s[wid][lane]*w3_s[lane];
      psum += __shfl_xor(psum,1); psum += __shfl_xor(psum,2); psum += __shfl_xor(psum,4);
      psum += __shfl_xor(psum,8); psum += __shfl_xor(psum,16);
      if (lane==0 && a<NA) out[a] = psum + B3;
    }
    __syncthreads();
  }
}

extern "C" void kernel_launch(void* const* d_in, const int* in_sizes, int n_in,
                              void* d_out, int out_size, void* d_ws, size_t ws_size,
                              hipStream_t stream) {
  (void)in_sizes; (void)n_in; (void)out_size; (void)ws_size;
  const int*   z    = (const int*)  d_in[0];
  const float* pos  = (const float*)d_in[1];
  const int*   ei   = (const int*)  d_in[2];
  const float* emb  = (const float*)d_in[3];
  const float* mw1  = (const float*)d_in[4];
  const float* mb1  = (const float*)d_in[5];
  const float* mw2  = (const float*)d_in[6];
  const float* mb2  = (const float*)d_in[7];
  const float* l1w  = (const float*)d_in[8];
  const float* l2w  = (const float*)d_in[9];
  const float* l2b  = (const float*)d_in[10];
  const float* ilw  = (const float*)d_in[11];
  const float* ilb  = (const float*)d_in[12];
  const float* hw1  = (const float*)d_in[13];
  const float* hb1  = (const float*)d_in[14];
  const float* a1   = (const float*)d_in[15];
  const float* hw2  = (const float*)d_in[16];
  const float* hb2  = (const float*)d_in[17];
  const float* a2   = (const float*)d_in[18];
  const float* hw3  = (const float*)d_in[19];
  const float* hb3  = (const float*)d_in[20];
  float* out = (float*)d_out;

  char* w = (char*)d_ws;
  uint2* ep2 = (uint2*)w; w += (size_t)NE*8;
  float* h   = (float*)w; w += (size_t)NA*128*4;
  u16*  aggb = (u16*)w;   w += (size_t)NAP*128*2;
  u16*  x    = (u16*)w;   w += (size_t)NAP*128*2;
  float* T   = (float*)w; w += (size_t)NL*NK*128*4;
  u32*  T2   = (u32*)w;   w += (size_t)NL*NK*128*4;
  u16* l1t   = (u16*)w;   w += (size_t)NL*16384*2;
  u16* l2t   = (u16*)w;   w += (size_t)NL*16384*2;
  u16* ilt   = (u16*)w;   w += (size_t)NL*16384*2;

  k_prep_w<<<(3*NL*16384+255)/256, 256, 0, stream>>>(l1w, l2w, ilw, l1t, l2t, ilt);
  k_table<<<NL*NK, 128, 0, stream>>>(mw1, mb1, mw2, mb2, T);
  k_pack<<<(NL*NK*128+255)/256, 256, 0, stream>>>(T, T2);
  k_prep_e<<<NE/256, 256, 0, stream>>>(pos, ei, ep2);
  k_embed<<<NA*128/256, 256, 0, stream>>>(z, emb, h);
  for (int l=0;l<NL;l++){
    k_lin1<<<(NA+127)/128, 256, 65536, stream>>>(h, l1t + l*16384, x);
    k_edge<<<NA/4, 256, 0, stream>>>(ep2, x, T2 + (size_t)l*NK*128, aggb);
    k_node<<<(NA+127)/128, 256, 65536, stream>>>(aggb, l2t+l*16384, l2b+l*128, ilt+l*16384, ilb+l*128, h);
  }
  k_head<<<(NA+31)/32, 256, 0, stream>>>(h, hw1, hb1, a1, hw2, hb2, a2, hw3, hb3, out);
}

// Round 3
// 638.430 us; speedup vs baseline: 1.6827x; 1.1495x over previous
//
#include <hip/hip_runtime.h>

#define NA 50000
#define NAP 50048
#define NE 1600000
#define NK 2048
#define NL 6

typedef __attribute__((ext_vector_type(8))) short short8;
typedef __attribute__((ext_vector_type(4))) float f32x4;
typedef unsigned short u16;
typedef unsigned int u32;

__device__ __forceinline__ float bf2f(u16 b){ union{u32 i;float f;}v; v.i=((u32)b)<<16; return v.f; }
__device__ __forceinline__ u16 f2bf(float f){ union{float f;u32 i;}v; v.f=f; u32 x=v.i; return (u16)((x + 0x7fffu + ((x>>16)&1u))>>16); }
__device__ __forceinline__ float sspf(float x){ return __logf(1.f+__expf(x)) - 0.69314718056f; }

// ---------------- prep: transpose node weights to bf16 [f_out][k] ----------------
__global__ __launch_bounds__(256) void k_prep_w(const float* __restrict__ l1,
    const float* __restrict__ l2, const float* __restrict__ il,
    u16* __restrict__ l1t, u16* __restrict__ l2t, u16* __restrict__ ilt)
{
  int t = blockIdx.x*256 + threadIdx.x;
  if (t >= 3*NL*16384) return;
  int sec = t / (NL*16384);
  int r = t % (NL*16384);
  int l = r / 16384, q = r & 16383;
  int fo = q >> 7, k = q & 127;
  const float* src = sec==0 ? l1 : (sec==1 ? l2 : il);
  u16* dst = sec==0 ? l1t : (sec==1 ? l2t : ilt);
  dst[r] = f2bf(src[l*16384 + k*128 + fo]);
}

// ---------------- prep: head weights -> bf16 [col][k], zero-padded to 128x128 ----------------
__global__ __launch_bounds__(256) void k_prep_wh(const float* __restrict__ hw1,
    const float* __restrict__ hw2, u16* __restrict__ w1t, u16* __restrict__ w2t)
{
  int t = blockIdx.x*256 + threadIdx.x;
  if (t >= 2*16384) return;
  int sec = t >> 14, q = t & 16383;
  int c = q >> 7, k = q & 127;
  if (sec == 0){
    w1t[q] = (c < 64) ? f2bf(hw1[k*64 + c]) : (u16)0;
  } else {
    w2t[q] = (c < 32 && k < 64) ? f2bf(hw2[k*32 + c]) : (u16)0;
  }
}

// ---------------- prep: per-edge distance -> packed (col|j<<17, fp16 u0,u1) ----------------
__global__ __launch_bounds__(256) void k_prep_e(const float* __restrict__ pos,
    const int* __restrict__ ei, uint2* __restrict__ ep2)
{
  int e = blockIdx.x*256 + threadIdx.x;
  if (e >= NE) return;
  int r = ei[e], c = ei[NE+e];
  float dx = pos[r*3+0]-pos[c*3+0];
  float dy = pos[r*3+1]-pos[c*3+1];
  float dz = pos[r*3+2]-pos[c*3+2];
  float d = sqrtf(dx*dx+dy*dy+dz*dz);
  float C = 0.5f*(cosf(d*0.31415926535f)+1.0f);
  float s = d * ((float)(NK-1) / 8.6603f);
  int j = (int)s;
  if (j > NK-2) j = NK-2;
  float w = s - (float)j;
  float u0 = C*(1.f-w), u1 = C*w;
  union { _Float16 h[2]; u32 u; } p;
  p.h[0] = (_Float16)u0; p.h[1] = (_Float16)u1;
  uint2 o; o.x = (u32)c | ((u32)j<<17); o.y = p.u;
  ep2[e] = o;
}

// ---------------- filter table: T[l][j][f] = (ssp(rbf(d_j)@W1+b1)@W2+b2)[f], exact fp32 ----------------
__global__ __launch_bounds__(128) void k_table(const float* __restrict__ w1,
    const float* __restrict__ b1, const float* __restrict__ w2,
    const float* __restrict__ b2, float* __restrict__ T)
{
  int l = blockIdx.x / NK, j = blockIdx.x % NK;
  __shared__ float rbf_s[50];
  __shared__ float h1_s[128];
  int t = threadIdx.x;
  float d = (float)j * (8.6603f/(float)(NK-1));
  if (t < 50){
    const float step = 10.0f/49.0f;
    const float coeff = -0.5f/(step*step);
    float dd = d - (float)t*step;
    rbf_s[t] = expf(coeff*dd*dd);
  }
  __syncthreads();
  const float* W1 = w1 + l*50*128;
  float acc = b1[l*128+t];
  for (int g=0; g<50; g++) acc += rbf_s[g]*W1[g*128+t];
  h1_s[t] = logf(1.0f+expf(acc)) - 0.69314718055994531f;
  __syncthreads();
  const float* W2 = w2 + l*128*128;
  float a2 = b2[l*128+t];
  for (int k=0;k<128;k++) a2 += h1_s[k]*W2[k*128+t];
  T[((size_t)l*NK + j)*128 + t] = a2;
}

// ---------------- pack table to bf16 knot-pairs: T2[j][f] = (T[j][f], T[j+1][f]) ----------------
__global__ __launch_bounds__(256) void k_pack(const float* __restrict__ T, u32* __restrict__ T2)
{
  int t = blockIdx.x*256 + threadIdx.x;
  if (t >= NL*NK*128) return;
  int jj = (t>>7) & (NK-1);
  float a = T[t];
  float b = (jj < NK-1) ? T[t+128] : a;
  T2[t] = (u32)f2bf(a) | ((u32)f2bf(b)<<16);
}

// ---------------- shared GEMM pieces (128x128 tile, bf16 MFMA, XOR-swizzled LDS) ----------------
__device__ __forceinline__ void stage_a_f32(const float* __restrict__ g, u16* l, int r0, int t){
  #pragma unroll
  for (int p=0;p<8;p++){
    int idx = p*256+t;
    int row = idx>>4, c = idx&15;
    int gr = r0+row;
    float4 f0 = make_float4(0.f,0.f,0.f,0.f), f1 = make_float4(0.f,0.f,0.f,0.f);
    if (gr < NA){
      const float* gp = g + (size_t)gr*128 + c*8;
      f0 = *(const float4*)gp;
      f1 = *(const float4*)(gp+4);
    }
    short8 v;
    u16* pv=(u16*)&v;
    pv[0]=f2bf(f0.x); pv[1]=f2bf(f0.y); pv[2]=f2bf(f0.z); pv[3]=f2bf(f0.w);
    pv[4]=f2bf(f1.x); pv[5]=f2bf(f1.y); pv[6]=f2bf(f1.z); pv[7]=f2bf(f1.w);
    *(short8*)(l + row*128 + ((c^(row&7))<<3)) = v;
  }
}

// A-stage from bf16 source with per-block row offset (source padded to NAP rows)
__device__ __forceinline__ void stage_a_bf16(const u16* __restrict__ g, u16* l, int r0, int t){
  #pragma unroll
  for (int p=0;p<8;p++){
    int idx = p*256+t;
    int row = idx>>4, c = idx&15;
    short8 v = *(const short8*)(g + (size_t)(r0+row)*128 + c*8);
    *(short8*)(l + row*128 + ((c^(row&7))<<3)) = v;
  }
}

__device__ __forceinline__ void stage_b_bf16(const u16* __restrict__ g, u16* l, int t){
  const short8* src = (const short8*)g;
  #pragma unroll
  for (int p=0;p<8;p++){
    int idx=p*256+t;
    int row=idx>>4, c=idx&15;
    short8 v = src[idx];
    *(short8*)(l + row*128 + ((c^(row&7))<<3)) = v;
  }
}

__device__ __forceinline__ void zacc(f32x4 (&acc)[4][4]){
  #pragma unroll
  for (int m=0;m<4;m++)
    #pragma unroll
    for (int n=0;n<4;n++){
      acc[m][n][0]=0.f; acc[m][n][1]=0.f; acc[m][n][2]=0.f; acc[m][n][3]=0.f;
    }
}

__device__ __forceinline__ void gemm128(const u16* A, const u16* B, f32x4 (&acc)[4][4], int lane, int wm, int wn){
  const int lr = lane&15, lk = lane>>4;
  #pragma unroll
  for (int kc=0;kc<4;kc++){
    short8 av[4], bv[4];
    #pragma unroll
    for (int m=0;m<4;m++){
      int row = wm*64+m*16+lr;
      av[m] = *(const short8*)(A + row*128 + ((((kc<<2)|lk) ^ (row&7))<<3));
    }
    #pragma unroll
    for (int n=0;n<4;n++){
      int row = wn*64+n*16+lr;
      bv[n] = *(const short8*)(B + row*128 + ((((kc<<2)|lk) ^ (row&7))<<3));
    }
    #pragma unroll
    for (int m=0;m<4;m++)
      #pragma unroll
      for (int n=0;n<4;n++)
        acc[m][n] = __builtin_amdgcn_mfma_f32_16x16x32_bf16(av[m], bv[n], acc[m][n], 0, 0, 0);
  }
}

// ---------------- layer-0: h = emb[z]; x = bf16(h @ lin1_w[0]) ----------------
__global__ __launch_bounds__(256) void k_lin1e(const int* __restrict__ z,
    const float* __restrict__ emb, const u16* __restrict__ wt,
    float* __restrict__ h, u16* __restrict__ x)
{
  extern __shared__ char smem[];
  u16* a_s = (u16*)smem;
  u16* b_s = a_s + 16384;
  int t = threadIdx.x, lane = t&63, wid = t>>6;
  int r0 = blockIdx.x*128;
  #pragma unroll
  for (int p=0;p<8;p++){
    int idx = p*256+t;
    int row = idx>>4, c = idx&15;
    int gr = r0+row;
    float4 f0 = make_float4(0.f,0.f,0.f,0.f), f1 = make_float4(0.f,0.f,0.f,0.f);
    if (gr < NA){
      int zr = z[gr];
      const float* gp = emb + (size_t)zr*128 + c*8;
      f0 = *(const float4*)gp;
      f1 = *(const float4*)(gp+4);
      float* hp = h + (size_t)gr*128 + c*8;
      *(float4*)hp = f0;
      *(float4*)(hp+4) = f1;
    }
    short8 v;
    u16* pv=(u16*)&v;
    pv[0]=f2bf(f0.x); pv[1]=f2bf(f0.y); pv[2]=f2bf(f0.z); pv[3]=f2bf(f0.w);
    pv[4]=f2bf(f1.x); pv[5]=f2bf(f1.y); pv[6]=f2bf(f1.z); pv[7]=f2bf(f1.w);
    *(short8*)(a_s + row*128 + ((c^(row&7))<<3)) = v;
  }
  stage_b_bf16(wt, b_s, t);
  __syncthreads();
  f32x4 acc[4][4]; zacc(acc);
  int wm=wid>>1, wn=wid&1;
  gemm128(a_s,b_s,acc,lane,wm,wn);
  int lr=lane&15, lk=lane>>4;
  #pragma unroll
  for (int n=0;n<4;n++){
    int f = wn*64+n*16+lr;
    #pragma unroll
    for (int m=0;m<4;m++){
      int rb = wm*64+m*16+(lk<<2);
      #pragma unroll
      for (int i=0;i<4;i++){
        int gr = r0+rb+i;
        if (gr < NA) x[(size_t)gr*128+f] = f2bf(acc[m][n][i]);
      }
    }
  }
}

// ---------------- per-edge: aggb[a][f] = bf16( sum_e lerp(T2,d_e)[f]*x[col_e][f] ) ----------------
__global__ __launch_bounds__(256) void k_edge(const uint2* __restrict__ ep2,
    const u16* __restrict__ x, const u32* __restrict__ T2, u16* __restrict__ aggb)
{
  __shared__ uint2 eps_s[128];
  int t = threadIdx.x;
  if (t < 128) eps_s[t] = ep2[(size_t)blockIdx.x*128 + t];
  __syncthreads();
  int lane = t&63, wid = t>>6;
  int g = lane>>4, q = lane&15;
  float acc[8];
  #pragma unroll
  for (int i=0;i<8;i++) acc[i]=0.f;
  #pragma unroll
  for (int it=0; it<8; it++){
    uint2 pr = eps_s[wid*32 + it*4 + g];
    u32 col = pr.x & 0x1FFFFu;
    u32 j   = pr.x >> 17;
    union { _Float16 h[2]; u32 u; } uu; uu.u = pr.y;
    float u0 = (float)uu.h[0], u1 = (float)uu.h[1];
    const int4*  tr = (const int4*)(T2 + ((size_t)j<<7));
    const uint2* xr = (const uint2*)(x + ((size_t)col<<7));
    #pragma unroll
    for (int s2=0; s2<2; s2++){
      int4  tv = tr[s2*16+q];
      uint2 xv = xr[s2*16+q];
      u32 tw[4] = {(u32)tv.x,(u32)tv.y,(u32)tv.z,(u32)tv.w};
      u32 xw[2] = {xv.x, xv.y};
      #pragma unroll
      for (int i=0;i<4;i++){
        union{u32 i;float f;} lo, hi, xf;
        lo.i = tw[i]<<16;
        hi.i = tw[i] & 0xffff0000u;
        u32 xq = xw[i>>1];
        xf.i = (i&1) ? (xq & 0xffff0000u) : (xq<<16);
        acc[s2*4+i] += (u0*lo.f + u1*hi.f) * xf.f;
      }
    }
  }
  #pragma unroll
  for (int i=0;i<8;i++){
    acc[i] += __shfl_xor(acc[i],16);
    acc[i] += __shfl_xor(acc[i],32);
  }
  if (lane < 16){
    int a = blockIdx.x*4 + wid;
    #pragma unroll
    for (int s2=0; s2<2; s2++){
      u32 p01 = (u32)f2bf(acc[s2*4+0]) | ((u32)f2bf(acc[s2*4+1])<<16);
      u32 p23 = (u32)f2bf(acc[s2*4+2]) | ((u32)f2bf(acc[s2*4+3])<<16);
      ((uint2*)(aggb + ((size_t)a<<7)))[s2*16+q] = make_uint2(p01,p23);
    }
  }
}

// ---------------- h += ssp(agg@lin2+b)@int_lin + b ; optionally x = bf16(h_new @ lin1_w[l+1]) ----------------
template<int CX>
__global__ __launch_bounds__(256) void k_node2(const u16* __restrict__ aggb,
    const u16* __restrict__ l2t, const float* __restrict__ l2b,
    const u16* __restrict__ ilt, const float* __restrict__ ilb,
    float* __restrict__ h, const u16* __restrict__ l1tn, u16* __restrict__ x)
{
  extern __shared__ char smem[];
  u16* a_s=(u16*)smem; u16* b_s=a_s+16384;
  int t=threadIdx.x, lane=t&63, wid=t>>6;
  int r0=blockIdx.x*128;
  stage_a_bf16(aggb, a_s, r0, t);
  stage_b_bf16(l2t, b_s, t);
  __syncthreads();
  f32x4 acc[4][4]; zacc(acc);
  int wm=wid>>1, wn=wid&1, lr=lane&15, lk=lane>>4;
  gemm128(a_s,b_s,acc,lane,wm,wn);
  __syncthreads();
  #pragma unroll
  for (int n=0;n<4;n++){
    int f=wn*64+n*16+lr;
    float bb=l2b[f];
    #pragma unroll
    for (int m=0;m<4;m++){
      int rb=wm*64+m*16+(lk<<2);
      #pragma unroll
      for (int i=0;i<4;i++){
        int r=rb+i;
        float v=sspf(acc[m][n][i]+bb);
        a_s[r*128 + (((f>>3)^(r&7))<<3) + (f&7)] = f2bf(v);
      }
    }
  }
  stage_b_bf16(ilt, b_s, t);
  __syncthreads();
  f32x4 acc2[4][4]; zacc(acc2);
  gemm128(a_s,b_s,acc2,lane,wm,wn);
  __syncthreads();
  #pragma unroll
  for (int n=0;n<4;n++){
    int f=wn*64+n*16+lr;
    float bb=ilb[f];
    #pragma unroll
    for (int m=0;m<4;m++){
      int rb=wm*64+m*16+(lk<<2);
      #pragma unroll
      for (int i=0;i<4;i++){
        int gr=r0+rb+i;
        int r=rb+i;
        u16 hb=0;
        if (gr<NA){
          size_t o=(size_t)gr*128+f;
          float hv = h[o] + acc2[m][n][i]+bb;
          h[o]=hv;
          hb=f2bf(hv);
        }
        if (CX) a_s[r*128 + (((f>>3)^(r&7))<<3) + (f&7)] = hb;
      }
    }
  }
  if (CX){
    stage_b_bf16(l1tn, b_s, t);
    __syncthreads();
    f32x4 acc3[4][4]; zacc(acc3);
    gemm128(a_s,b_s,acc3,lane,wm,wn);
    #pragma unroll
    for (int n=0;n<4;n++){
      int f=wn*64+n*16+lr;
      #pragma unroll
      for (int m=0;m<4;m++){
        int rb=wm*64+m*16+(lk<<2);
        #pragma unroll
        for (int i=0;i<4;i++){
          int gr=r0+rb+i;
          if (gr<NA) x[(size_t)gr*128+f] = f2bf(acc3[m][n][i]);
        }
      }
    }
  }
}

// ---------------- head via MFMA: out = prelu(prelu(h@w1+b1)@w2+b2)@w3+b3 ----------------
__global__ __launch_bounds__(256) void k_head2(const float* __restrict__ h,
    const u16* __restrict__ w1t, const u16* __restrict__ w2t,
    const float* __restrict__ hb1, const float* __restrict__ a1p,
    const float* __restrict__ hb2, const float* __restrict__ a2p,
    const float* __restrict__ hw3, const float* __restrict__ hb3,
    float* __restrict__ out)
{
  extern __shared__ char smem[];
  u16* a_s=(u16*)smem; u16* b_s=a_s+16384;
  int t=threadIdx.x, lane=t&63, wid=t>>6;
  int r0=blockIdx.x*128;
  stage_a_f32(h, a_s, r0, t);
  stage_b_bf16(w1t, b_s, t);
  __syncthreads();
  f32x4 acc[4][4]; zacc(acc);
  int wm=wid>>1, wn=wid&1, lr=lane&15, lk=lane>>4;
  gemm128(a_s,b_s,acc,lane,wm,wn);
  __syncthreads();
  float A1=a1p[0], A2=a2p[0];
  // y1 = prelu(acc + b1) for f<64 -> a_s bf16 swizzled (k<64 region)
  if (wn==0){
    #pragma unroll
    for (int n=0;n<4;n++){
      int f=n*16+lr;
      float bb=hb1[f];
      #pragma unroll
      for (int m=0;m<4;m++){
        int rb=wm*64+m*16+(lk<<2);
        #pragma unroll
        for (int i=0;i<4;i++){
          int r=rb+i;
          float v=acc[m][n][i]+bb;
          v = v>=0.f ? v : A1*v;
          a_s[r*128 + (((f>>3)^(r&7))<<3) + (f&7)] = f2bf(v);
        }
      }
    }
  }
  stage_b_bf16(w2t, b_s, t);
  __syncthreads();
  f32x4 acc2[4][4]; zacc(acc2);
  gemm128(a_s,b_s,acc2,lane,wm,wn);
  __syncthreads();
  // y2 = prelu(acc2 + b2) for f<32 -> fp32 LDS [128][33]
  float* y2s = (float*)smem;   // 128*33*4 = 16896 B, a_s region is free now
  if (wn==0){
    #pragma unroll
    for (int n=0;n<2;n++){
      int f=n*16+lr;
      float bb=hb2[f];
      #pragma unroll
      for (int m=0;m<4;m++){
        int rb=wm*64+m*16+(lk<<2);
        #pragma unroll
        for (int i=0;i<4;i++){
          int r=rb+i;
          float v=acc2[m][n][i]+bb;
          y2s[r*33+f] = v>=0.f ? v : A2*v;
        }
      }
    }
  }
  __syncthreads();
  if (t < 128){
    int gr = r0+t;
    float s = hb3[0];
    #pragma unroll
    for (int k=0;k<32;k++) s += y2s[t*33+k]*hw3[k];
    if (gr < NA) out[gr] = s;
  }
}

extern "C" void kernel_launch(void* const* d_in, const int* in_sizes, int n_in,
                              void* d_out, int out_size, void* d_ws, size_t ws_size,
                              hipStream_t stream) {
  (void)in_sizes; (void)n_in; (void)out_size; (void)ws_size;
  const int*   z    = (const int*)  d_in[0];
  const float* pos  = (const float*)d_in[1];
  const int*   ei   = (const int*)  d_in[2];
  const float* emb  = (const float*)d_in[3];
  const float* mw1  = (const float*)d_in[4];
  const float* mb1  = (const float*)d_in[5];
  const float* mw2  = (const float*)d_in[6];
  const float* mb2  = (const float*)d_in[7];
  const float* l1w  = (const float*)d_in[8];
  const float* l2w  = (const float*)d_in[9];
  const float* l2b  = (const float*)d_in[10];
  const float* ilw  = (const float*)d_in[11];
  const float* ilb  = (const float*)d_in[12];
  const float* hw1  = (const float*)d_in[13];
  const float* hb1  = (const float*)d_in[14];
  const float* a1   = (const float*)d_in[15];
  const float* hw2  = (const float*)d_in[16];
  const float* hb2  = (const float*)d_in[17];
  const float* a2   = (const float*)d_in[18];
  const float* hw3  = (const float*)d_in[19];
  const float* hb3  = (const float*)d_in[20];
  float* out = (float*)d_out;

  char* w = (char*)d_ws;
  uint2* ep2 = (uint2*)w; w += (size_t)NE*8;
  float* h   = (float*)w; w += (size_t)NA*128*4;
  u16*  aggb = (u16*)w;   w += (size_t)NAP*128*2;
  u16*  x    = (u16*)w;   w += (size_t)NAP*128*2;
  float* T   = (float*)w; w += (size_t)NL*NK*128*4;
  u32*  T2   = (u32*)w;   w += (size_t)NL*NK*128*4;
  u16* l1t   = (u16*)w;   w += (size_t)NL*16384*2;
  u16* l2t   = (u16*)w;   w += (size_t)NL*16384*2;
  u16* ilt   = (u16*)w;   w += (size_t)NL*16384*2;
  u16* w1t   = (u16*)w;   w += (size_t)16384*2;
  u16* w2t   = (u16*)w;   w += (size_t)16384*2;

  const int nblk = (NA+127)/128;
  k_prep_w<<<(3*NL*16384+255)/256, 256, 0, stream>>>(l1w, l2w, ilw, l1t, l2t, ilt);
  k_prep_wh<<<(2*16384+255)/256, 256, 0, stream>>>(hw1, hw2, w1t, w2t);
  k_table<<<NL*NK, 128, 0, stream>>>(mw1, mb1, mw2, mb2, T);
  k_pack<<<(NL*NK*128+255)/256, 256, 0, stream>>>(T, T2);
  k_prep_e<<<NE/256, 256, 0, stream>>>(pos, ei, ep2);
  k_lin1e<<<nblk, 256, 65536, stream>>>(z, emb, l1t, h, x);
  for (int l=0;l<NL;l++){
    k_edge<<<NA/4, 256, 0, stream>>>(ep2, x, T2 + (size_t)l*NK*128, aggb);
    if (l < NL-1)
      k_node2<1><<<nblk, 256, 65536, stream>>>(aggb, l2t+l*16384, l2b+l*128,
          ilt+l*16384, ilb+l*128, h, l1t+(l+1)*16384, x);
    else
      k_node2<0><<<nblk, 256, 65536, stream>>>(aggb, l2t+l*16384, l2b+l*128,
          ilt+l*16384, ilb+l*128, h, (const u16*)nullptr, (u16*)nullptr);
  }
  k_head2<<<nblk, 256, 65536, stream>>>(h, w1t, w2t, hb1, a1, hb2, a2, hw3, hb3, out);
}